// Round 2
// 203.764 us; speedup vs baseline: 1.0160x; 1.0160x over previous
//
#include <hip/hip_runtime.h>

// ---------------------------------------------------------------------------
// CustomAttention: cosine-sim MHA.  N=1024 seq, B=4 batch, C=1024, H=16, hd=64
// R7: flash was latency-bound, not throughput-bound (MfmaUtil 14%, VALU 45%,
//     HBM 6%, occ 17.7% -- nothing saturated).  Per-kt chain was serial:
//     GLOAD -> barrier(vmcnt0 drain = full load latency) -> compute -> barrier.
//     Fix: double-buffered K/V, prefetch kt+1 issued AFTER the single
//     per-kt barrier so loads overlap the whole compute phase; barriers/kt
//     2 -> 1.  Plus: __builtin_amdgcn_exp2f (bare v_exp_f32, not the OCML
//     libcall), v_cvt_pkrtz packing for P, s_setprio(1) around MFMA clusters.
//     proj/out/cvt unchanged from R5.
//     (R7b: cvt_pkrtz returns __fp16x2, union member type fixed.)
// ---------------------------------------------------------------------------

typedef _Float16 f16x8 __attribute__((ext_vector_type(8)));
typedef __fp16   h16x2 __attribute__((ext_vector_type(2)));
typedef float    f32x4 __attribute__((ext_vector_type(4)));

#define LOG2E 1.4426950408889634f
#define LOGMAX 4.6051702f   // log(100)

#define GLOAD16(g, l) \
    __builtin_amdgcn_global_load_lds((__attribute__((address_space(1))) void*)(g), \
                                     (__attribute__((address_space(3))) void*)(l), 16, 0, 0)

__device__ __forceinline__ unsigned short f2h(float x) {
    union { _Float16 h; unsigned short u; } cv;
    cv.h = (_Float16)x;
    return cv.u;
}

// ---- fp32 -> fp16 convert, all 5 tensors in one launch ----
__global__ __launch_bounds__(256) void cvt_all(
    const float* __restrict__ q, const float* __restrict__ k,
    const float* __restrict__ v, const float* __restrict__ w,
    const float* __restrict__ ow,
    unsigned short* __restrict__ qbf, unsigned short* __restrict__ kbf,
    unsigned short* __restrict__ vbf, unsigned short* __restrict__ wbf,
    unsigned short* __restrict__ owbf)
{
    int b = blockIdx.x;
    const float* src; unsigned short* dst; int idx;
    if      (b < 4096)  { src = q;  dst = qbf;  idx = b; }
    else if (b < 8192)  { src = k;  dst = kbf;  idx = b - 4096; }
    else if (b < 12288) { src = v;  dst = vbf;  idx = b - 8192; }
    else if (b < 15360) { src = w;  dst = wbf;  idx = b - 12288; }
    else                { src = ow; dst = owbf; idx = b - 15360; }
    int i = idx * 256 + threadIdx.x;
    float4 val = ((const float4*)src)[i];
    ushort4 o;
    o.x = f2h(val.x); o.y = f2h(val.y); o.z = f2h(val.z); o.w = f2h(val.w);
    ((ushort4*)dst)[i] = o;
}

// ---- projection GEMM + fused l2norm epilogue (unchanged from R5) ----
__global__ __launch_bounds__(256) void proj_gemm(
    const unsigned short* __restrict__ qbf, const unsigned short* __restrict__ kbf,
    const unsigned short* __restrict__ vbf, const unsigned short* __restrict__ wbf,
    const float* __restrict__ bias, const float* __restrict__ lsc,
    unsigned short* __restrict__ qn, unsigned short* __restrict__ kn,
    unsigned short* __restrict__ vT)
{
    __shared__ __align__(16) unsigned short AsmF[128 * 64];
    __shared__ __align__(16) unsigned short BsmF[128 * 64];
    int tid = threadIdx.x;
    int lane = tid & 63, wave = tid >> 6;
    int lr = lane & 15, lq = lane >> 4;
    int wr = wave >> 1, wc = wave & 1;

    int lin = blockIdx.x;
    int xcd = lin & 7, s = lin >> 3;
    int xt = s & 7, yy = (s >> 3) & 3, z = s >> 5;
    int m0 = (xcd * 4 + yy) * 128, n0 = xt * 128;

    const unsigned short* A = (z == 0) ? qbf : (z == 1) ? kbf : vbf;
    const unsigned short* W = wbf + (size_t)z * 1024 * 1024;

    int rl = lane >> 3;
    int cg = ((lane & 7) ^ rl) << 3;                     // halves
    const unsigned short* gA = A + (size_t)(m0 + wave * 32 + rl) * 1024 + cg;
    const unsigned short* gB = W + (size_t)(n0 + wave * 32 + rl) * 1024 + cg;
    unsigned short* lA = &AsmF[wave * 32 * 64];
    unsigned short* lB = &BsmF[wave * 32 * 64];

    int swz = lr & 7;
    int c0 = (lq ^ swz) << 3;
    int c1 = ((lq ^ 4) ^ swz) << 3;

    f32x4 acc[4][4];
    for (int i = 0; i < 4; i++) for (int j = 0; j < 4; j++) acc[i][j] = (f32x4){0.f, 0.f, 0.f, 0.f};

    for (int ki = 0; ki < 16; ++ki) {
        for (int j = 0; j < 4; ++j) {
            GLOAD16(gA + ki * 64 + j * 8192, lA + j * 512);
            GLOAD16(gB + ki * 64 + j * 8192, lB + j * 512);
        }
        __syncthreads();
        for (int kc = 0; kc < 2; ++kc) {
            int co = kc ? c1 : c0;
            f16x8 af[4], bfr[4];
            for (int mi = 0; mi < 4; ++mi) af[mi]  = *(const f16x8*)&AsmF[(wr * 64 + mi * 16 + lr) * 64 + co];
            for (int ni = 0; ni < 4; ++ni) bfr[ni] = *(const f16x8*)&BsmF[(wc * 64 + ni * 16 + lr) * 64 + co];
            for (int mi = 0; mi < 4; ++mi)
                for (int ni = 0; ni < 4; ++ni)
                    acc[mi][ni] = __builtin_amdgcn_mfma_f32_16x16x32_f16(af[mi], bfr[ni], acc[mi][ni], 0, 0, 0);
        }
        __syncthreads();
    }

    int h = (n0 >> 6) + wc;
    float bv[4];
    for (int ni = 0; ni < 4; ++ni) bv[ni] = bias[z * 1024 + n0 + wc * 64 + ni * 16 + lr];
    for (int mi = 0; mi < 4; ++mi)
        for (int ni = 0; ni < 4; ++ni)
            for (int r = 0; r < 4; ++r) acc[mi][ni][r] += bv[ni];

    float lsfac = __expf(fminf(lsc[h], LOGMAX)) * LOG2E;

    for (int mi = 0; mi < 4; ++mi)
        for (int r = 0; r < 4; ++r) {
            int row = m0 + wr * 64 + mi * 16 + lq * 4 + r;   // m = n*4 + b
            int n = row >> 2, b = row & 3;
            int bh = b * 16 + h;
            if (z < 2) {
                float ss = 0.f;
                for (int ni = 0; ni < 4; ++ni) ss += acc[mi][ni][r] * acc[mi][ni][r];
                for (int off = 1; off < 16; off <<= 1) ss += __shfl_xor(ss, off);
                float scale = 1.0f / fmaxf(sqrtf(ss), 1e-12f);
                if (z == 0) scale *= lsfac;
                unsigned short* dst = (z == 0) ? qn : kn;
                for (int ni = 0; ni < 4; ++ni)
                    dst[(size_t)bh * 65536 + (size_t)n * 64 + ni * 16 + lr] = f2h(acc[mi][ni][r] * scale);
            } else {
                for (int ni = 0; ni < 4; ++ni)
                    vT[(size_t)bh * 65536 + (size_t)(ni * 16 + lr) * 1024 + n] = f2h(acc[mi][ni][r]);
            }
        }
}

// ---- flash attention: 128 q-rows/block, 2 q-groups per wave, dbuf K/V ----
// grid 512; XCD swizzle: xcd owns 8 heads x 8 q-tiles, qt fastest.
// Wave w, group g covers q-rows q0 + g*64 + w*16 + lr.  K/V frag reads are
// shared across both groups.  QK acc init = -off.  R7: K/V double-buffered,
// one barrier per kt; prefetch for kt+1 issued after the barrier so the
// implicit vmcnt(0) drain at the NEXT barrier is nearly free.
__global__ __launch_bounds__(256) void flash_kernel(
    const unsigned short* __restrict__ qn, const unsigned short* __restrict__ kn,
    const unsigned short* __restrict__ vT, const float* __restrict__ lsc,
    unsigned short* __restrict__ xb)
{
    __shared__ __align__(16) unsigned short K_flat[2][64 * 64];
    __shared__ __align__(16) unsigned short V_flat[2][64 * 64];     // [d][kpos]
    __shared__ __align__(16) unsigned short P_lds[4][2][16][72];    // [wave][grp][qrow][kpos]
    int tid = threadIdx.x;
    int lane = tid & 63, wave = tid >> 6;
    int lr = lane & 15, lq = lane >> 4;

    int lin = blockIdx.x;
    int xcd = lin & 7, s = lin >> 3;
    int qt = s & 7, bh = xcd * 8 + (s >> 3);
    int q0 = qt * 128;

    // static softmax offset folded into QK accumulator init
    float off = __expf(fminf(lsc[bh & 15], LOGMAX)) * LOG2E - 12.0f;
    f32x4 initv = (f32x4){-off, -off, -off, -off};

    f16x8 qf[2][2];   // [group][kc]  B-frag: Q[qrow][d]
    for (int g = 0; g < 2; ++g)
        for (int kc = 0; kc < 2; ++kc)
            qf[g][kc] = *(const f16x8*)(qn + (size_t)bh * 65536 +
                          (size_t)(q0 + g * 64 + wave * 16 + lr) * 64 + kc * 32 + lq * 8);

    int rl = lane >> 3;
    int cg = ((lane & 7) ^ rl) << 3;
    const unsigned short* gK = kn + (size_t)bh * 65536 + (size_t)(wave * 16 + rl) * 64 + cg;
    const unsigned short* gV = vT + (size_t)bh * 65536 + (size_t)(wave * 16 + rl) * 1024 + cg;
    int swz = lr & 7;
    int c0 = (lq ^ swz) << 3;
    int c1 = ((lq ^ 4) ^ swz) << 3;

    f32x4 o[2][4];    // [group][nt]  O^T[d][qrow]
    for (int g = 0; g < 2; ++g) for (int i = 0; i < 4; i++) o[g][i] = (f32x4){0.f, 0.f, 0.f, 0.f};
    float lsum[2] = {0.f, 0.f};

    // prologue: stage kt=0 into buffer 0
    {
        unsigned short* lK = &K_flat[0][wave * 16 * 64];
        unsigned short* lV = &V_flat[0][wave * 16 * 64];
        for (int j = 0; j < 2; ++j) {
            GLOAD16(gK + j * 512,  lK + j * 512);
            GLOAD16(gV + j * 8192, lV + j * 512);
        }
    }

    for (int kt = 0; kt < 16; ++kt) {
        int cur = kt & 1;
        __syncthreads();   // buffers[cur] staged by all waves; prev reads of buf[cur^1] done

        // prefetch kt+1 into the other buffer; has the whole compute phase to land
        if (kt < 15) {
            unsigned short* lK = &K_flat[cur ^ 1][wave * 16 * 64];
            unsigned short* lV = &V_flat[cur ^ 1][wave * 16 * 64];
            for (int j = 0; j < 2; ++j) {
                GLOAD16(gK + (kt + 1) * 4096 + j * 512,  lK + j * 512);
                GLOAD16(gV + (kt + 1) * 64  + j * 8192,  lV + j * 512);
            }
        }

        // S^T = K Q^T - off : one K-frag read feeds both q-groups
        f32x4 sc[2][4];
        __builtin_amdgcn_s_setprio(1);
        for (int ct = 0; ct < 4; ++ct) {
            for (int kc = 0; kc < 2; ++kc) {
                f16x8 kf = *(const f16x8*)&K_flat[cur][(ct * 16 + lr) * 64 + (kc ? c1 : c0)];
                for (int g = 0; g < 2; ++g)
                    sc[g][ct] = __builtin_amdgcn_mfma_f32_16x16x32_f16(
                        kf, qf[g][kc], kc == 0 ? initv : sc[g][ct], 0, 0, 0);
            }
        }
        __builtin_amdgcn_s_setprio(0);

        // p = exp2(sc); per-lane l accumulate; pack to wave/group-private LDS
        for (int g = 0; g < 2; ++g)
            for (int ct = 0; ct < 4; ++ct) {
                float p0 = __builtin_amdgcn_exp2f(sc[g][ct][0]);
                float p1 = __builtin_amdgcn_exp2f(sc[g][ct][1]);
                float p2 = __builtin_amdgcn_exp2f(sc[g][ct][2]);
                float p3 = __builtin_amdgcn_exp2f(sc[g][ct][3]);
                lsum[g] += (p0 + p1) + (p2 + p3);
                union { h16x2 h[2]; ushort4 u; } pw;
                pw.h[0] = __builtin_amdgcn_cvt_pkrtz(p0, p1);
                pw.h[1] = __builtin_amdgcn_cvt_pkrtz(p2, p3);
                *(ushort4*)&P_lds[wave][g][lr][ct * 16 + lq * 4] = pw.u;
            }

        // O^T += V^T @ P^T : one V-frag read feeds both groups
        f16x8 pf[2][2];
        for (int g = 0; g < 2; ++g)
            for (int kc = 0; kc < 2; ++kc)
                pf[g][kc] = *(const f16x8*)&P_lds[wave][g][lr][kc * 32 + lq * 8];
        __builtin_amdgcn_s_setprio(1);
        for (int nt = 0; nt < 4; ++nt)
            for (int kc = 0; kc < 2; ++kc) {
                f16x8 vf = *(const f16x8*)&V_flat[cur][(nt * 16 + lr) * 64 + (kc ? c1 : c0)];
                for (int g = 0; g < 2; ++g)
                    o[g][nt] = __builtin_amdgcn_mfma_f32_16x16x32_f16(vf, pf[g][kc], o[g][nt], 0, 0, 0);
            }
        __builtin_amdgcn_s_setprio(0);
    }

    int b = bh >> 4, h = bh & 15;
    for (int g = 0; g < 2; ++g) {
        float ls = lsum[g];
        ls += __shfl_xor(ls, 16);
        ls += __shfl_xor(ls, 32);
        float inv = 1.0f / ls;
        size_t m = (size_t)(q0 + g * 64 + wave * 16 + lr) * 4 + b;
        for (int nt = 0; nt < 4; ++nt) {
            ushort4 w;
            w.x = f2h(o[g][nt][0] * inv); w.y = f2h(o[g][nt][1] * inv);
            w.z = f2h(o[g][nt][2] * inv); w.w = f2h(o[g][nt][3] * inv);
            *(ushort4*)(xb + m * 1024 + h * 64 + nt * 16 + lq * 4) = w;
        }
    }
}

// ---- output GEMM: out(4096x1024) = X @ out_w^T + out_b;  128x64 tiles ----
__global__ __launch_bounds__(256) void out_gemm(
    const unsigned short* __restrict__ xb, const unsigned short* __restrict__ owbf,
    const float* __restrict__ bias, float* __restrict__ outp)
{
    __shared__ __align__(16) unsigned short AsmF[128 * 64];
    __shared__ __align__(16) unsigned short BsmF[64 * 64];
    int tid = threadIdx.x;
    int lane = tid & 63, wave = tid >> 6;
    int lr = lane & 15, lq = lane >> 4;

    int lin = blockIdx.x;
    int xcd = lin & 7, s = lin >> 3;
    int xt = s & 15, yy = s >> 4;
    int m0 = (xcd * 4 + yy) * 128, n0 = xt * 64;

    int rl = lane >> 3;
    int cg = ((lane & 7) ^ rl) << 3;
    const unsigned short* gA = xb   + (size_t)(m0 + wave * 32 + rl) * 1024 + cg;
    const unsigned short* gB = owbf + (size_t)(n0 + wave * 16 + rl) * 1024 + cg;
    unsigned short* lA = &AsmF[wave * 32 * 64];
    unsigned short* lB = &BsmF[wave * 16 * 64];
    int swz = lr & 7;
    int c0 = (lq ^ swz) << 3;
    int c1 = ((lq ^ 4) ^ swz) << 3;

    f32x4 acc[2][4];
    for (int i = 0; i < 2; i++) for (int j = 0; j < 4; j++) acc[i][j] = (f32x4){0.f, 0.f, 0.f, 0.f};

    for (int ki = 0; ki < 16; ++ki) {
        for (int j = 0; j < 4; ++j)
            GLOAD16(gA + ki * 64 + j * 8192, lA + j * 512);
        for (int j = 0; j < 2; ++j)
            GLOAD16(gB + ki * 64 + j * 8192, lB + j * 512);
        __syncthreads();
        for (int kc = 0; kc < 2; ++kc) {
            int co = kc ? c1 : c0;
            f16x8 af[2], bfr[4];
            for (int mi = 0; mi < 2; ++mi) af[mi]  = *(const f16x8*)&AsmF[(wave * 32 + mi * 16 + lr) * 64 + co];
            for (int ni = 0; ni < 4; ++ni) bfr[ni] = *(const f16x8*)&BsmF[(ni * 16 + lr) * 64 + co];
            for (int mi = 0; mi < 2; ++mi)
                for (int ni = 0; ni < 4; ++ni)
                    acc[mi][ni] = __builtin_amdgcn_mfma_f32_16x16x32_f16(af[mi], bfr[ni], acc[mi][ni], 0, 0, 0);
        }
        __syncthreads();
    }
    for (int mi = 0; mi < 2; ++mi)
        for (int ni = 0; ni < 4; ++ni)
            for (int r = 0; r < 4; ++r) {
                int row = m0 + wave * 32 + mi * 16 + lq * 4 + r;
                int col = n0 + ni * 16 + lr;
                outp[(size_t)row * 1024 + col] = acc[mi][ni][r] + bias[col];
            }
}

extern "C" void kernel_launch(void* const* d_in, const int* in_sizes, int n_in,
                              void* d_out, int out_size, void* d_ws, size_t ws_size,
                              hipStream_t stream) {
    const float* query = (const float*)d_in[0];
    const float* key   = (const float*)d_in[1];
    const float* value = (const float*)d_in[2];
    const float* ipw   = (const float*)d_in[3];
    const float* ipb   = (const float*)d_in[4];
    const float* lsc   = (const float*)d_in[5];
    const float* ow    = (const float*)d_in[6];
    const float* ob    = (const float*)d_in[7];
    float* outp = (float*)d_out;

    char* ws = (char*)d_ws;
    unsigned short* qbf  = (unsigned short*)(ws);               // 8 MB fp16 query
    unsigned short* kbf  = (unsigned short*)(ws + 8388608);     // 8 MB
    unsigned short* vbf  = (unsigned short*)(ws + 16777216);    // 8 MB
    unsigned short* wbf  = (unsigned short*)(ws + 25165824);    // 6 MB in_proj_w
    unsigned short* owbf = (unsigned short*)(ws + 31457280);    // 2 MB out_w
    unsigned short* qn   = (unsigned short*)(ws + 33554432);    // 8 MB normalized q (bh,n,d)
    unsigned short* kn   = (unsigned short*)(ws + 41943040);    // 8 MB normalized k
    unsigned short* vT   = (unsigned short*)(ws + 50331648);    // 8 MB v^T (bh,d,n)
    unsigned short* xbuf = (unsigned short*)(ws + 58720256);    // 8 MB attn out (m, c) row-major

    cvt_all<<<16384, 256, 0, stream>>>(query, key, value, ipw, ow,
                                       qbf, kbf, vbf, wbf, owbf);
    proj_gemm<<<768, 256, 0, stream>>>(qbf, kbf, vbf, wbf, ipb, lsc, qn, kn, vT);
    flash_kernel<<<512, 256, 0, stream>>>(qn, kn, vT, lsc, xbuf);
    out_gemm<<<512, 256, 0, stream>>>(xbuf, owbf, ob, outp);
}